// Round 2
// baseline (208.230 us; speedup 1.0000x reference)
//
#include <hip/hip_runtime.h>
#include <math.h>

#define BB 64
#define LL 1024
#define HH 256
#define TT 128
#define D_ID 128
#define D_SZ 64
#define D_POS 128
#define DX 192   // D_ID + D_SZ

typedef short s16x8 __attribute__((ext_vector_type(8)));
typedef float f32x16 __attribute__((ext_vector_type(16)));
typedef unsigned short u16x8 __attribute__((ext_vector_type(8)));
typedef unsigned short u16x4 __attribute__((ext_vector_type(4)));

__device__ __forceinline__ unsigned short f2bf(float f) {
    unsigned u = __float_as_uint(f);
    unsigned r = u + 0x7fffu + ((u >> 16) & 1u);   // RNE
    return (unsigned short)(r >> 16);
}

__device__ __forceinline__ s16x8 pack8(float4 a, float4 b) {
    u16x8 p;
    p[0] = f2bf(a.x); p[1] = f2bf(a.y); p[2] = f2bf(a.z); p[3] = f2bf(a.w);
    p[4] = f2bf(b.x); p[5] = f2bf(b.y); p[6] = f2bf(b.z); p[7] = f2bf(b.w);
    return (s16x8)p;
}

// =====================================================================
// D1 prep: three independent jobs in one grid.
//   [0,112):    embed  -> xh_t[448][64] = concat(x, h0)^T   (round-0 form)
//   [112,176):  sv/rv dots for t<127 (h_new-independent)
//   [176,1200): convert obj_id_table fp32 -> qT bf16 (16 MB streaming;
//               L3-resident for attn's gather; same f2bf RNE as before)
// =====================================================================
__global__ void prep_kernel(const int* __restrict__ obj_id,
                            const int* __restrict__ obj_size,
                            const float* __restrict__ h0,
                            const float* __restrict__ obj_id_table,
                            const float* __restrict__ obj_size_table,
                            const float* __restrict__ history,
                            const float* __restrict__ pos_table,
                            const float* __restrict__ scorer_W,
                            const float* __restrict__ reuse_W,
                            float* __restrict__ xh_t,
                            float* __restrict__ sv,
                            float* __restrict__ rv,
                            unsigned short* __restrict__ qT) {
    int blk = blockIdx.x;
    int tid = threadIdx.x;

    if (blk < 112) {
        // ---- embed: xh_t[k][b]
        int b = tid & 63;
        int k = blk * 4 + (tid >> 6);
        float v;
        if (k < D_ID)      v = obj_id_table[(size_t)obj_id[b] * D_ID + k];
        else if (k < DX)   v = obj_size_table[(size_t)obj_size[b] * D_SZ + (k - D_ID)];
        else               v = h0[b * HH + (k - DX)];
        xh_t[k * 64 + b] = v;
        return;
    }

    if (blk < 176) {
        // ---- sv/rv: b = blk-112, thread -> (which = tid>>7, t = tid&127)
        int b = blk - 112;
        int which = tid >> 7;
        int t = tid & 127;
        if (t == TT - 1) return;        // t=127 handled inside attn_kernel
        const float* w = which ? reuse_W : scorer_W;
        const float* hrow = history + ((size_t)b * (TT - 1) + t) * HH;
        float acc = 0.f;
#pragma unroll 8
        for (int k = 0; k < HH / 4; ++k) {
            float4 hv = *(const float4*)(hrow + 4 * k);
            float4 wv = *(const float4*)(w + 4 * k);
            acc += hv.x * wv.x + hv.y * wv.y + hv.z * wv.z + hv.w * wv.w;
        }
        const float* prow = pos_table + (size_t)t * D_POS;
#pragma unroll 8
        for (int k = 0; k < D_POS / 4; ++k) {
            float4 pv = *(const float4*)(prow + 4 * k);
            float4 wv = *(const float4*)(w + HH + 4 * k);
            acc += pv.x * wv.x + pv.y * wv.y + pv.z * wv.z + pv.w * wv.w;
        }
        (which ? rv : sv)[b * TT + t] = acc;
        return;
    }

    // ---- table convert: 262144 threads x 32 floats = 8M elems
    {
        size_t t0 = ((size_t)(blk - 176) * 256 + tid) * 32;
        const float* src = obj_id_table + t0;
        unsigned short* dst = qT + t0;
#pragma unroll
        for (int i = 0; i < 4; ++i) {
            float4 a = *(const float4*)(src + i * 8);
            float4 b = *(const float4*)(src + i * 8 + 4);
            *(s16x8*)(dst + i * 8) = pack8(a, b);
        }
    }
}

// =====================================================================
// D2 gates (round-0 form): grid 256 (one j per block), block 256.
//   wave q owns W row q*HH+j (wave-uniform -> scalar loads);
//   xh_t read k-major from L2, coalesced across b lanes.
// =====================================================================
__global__ void gates_kernel(const float* __restrict__ xh_t,
                             const float* __restrict__ W_ih,
                             const float* __restrict__ W_hh,
                             const float* __restrict__ b_ih,
                             const float* __restrict__ b_hh,
                             const float* __restrict__ c0,
                             float* __restrict__ h_new) {
    int j = blockIdx.x;
    int tid = threadIdx.x;
    int b = tid & 63;
    int q = __builtin_amdgcn_readfirstlane(tid >> 6);
    int r = q * HH + j;
    __shared__ float gS[256];

    float acc = b_ih[r] + b_hh[r];
    const float* wi = W_ih + (size_t)r * DX;
    const float* wh = W_hh + (size_t)r * HH;
#pragma unroll 16
    for (int k = 0; k < DX; ++k)
        acc += wi[k] * xh_t[k * 64 + b];
#pragma unroll 16
    for (int k = 0; k < HH; ++k)
        acc += wh[k] * xh_t[(DX + k) * 64 + b];
    gS[q * 64 + b] = acc;
    __syncthreads();

    if (tid < 64) {
        float ig = 1.f / (1.f + expf(-gS[tid]));
        float fg = 1.f / (1.f + expf(-gS[64 + tid]));
        float gg = tanhf(gS[128 + tid]);
        float og = 1.f / (1.f + expf(-gS[192 + tid]));
        float c = fg * c0[tid * HH + j] + ig * gg;
        h_new[tid * HH + j] = og * tanhf(c);
    }
}

// =====================================================================
// D3 attn: per block (b, 128-l tile), 4 waves, wave w -> 32 l rows.
//   1. Q gather DIRECT TO REGISTERS from bf16 qT (no LDS, no barrier):
//      lane (ln,half) owns row l = l0+32w+ln and loads its 8 A-fragments
//      qf[ks] = qT[cl][ks*16+half*8 .. +8]. Issued first; ~900cy HBM
//      latency hides under the hp-projection MFMAs below.
//   2. hp projection (8x redundant per b, overlapped with 1.): MFMA with
//      A=attn_W rows (M=d), B=hist rows (N=t); bf16 C written straight
//      into hpS in the score-MFMA's fragment layout.
//   3. waves 0/1: sv/rv at t=127 (needs h_new)
//   4. one barrier; scores = Q@hp^T, softmax over t, heads.
//   LDS = 32 KB (hpS) + 8 B, VGPR ~180.
// =====================================================================
__global__ void attn_kernel(const int* __restrict__ cache_lines,
                            const unsigned short* __restrict__ qT,
                            const float* __restrict__ history,
                            const float* __restrict__ h_new,
                            const float* __restrict__ attn_W,
                            const float* __restrict__ pos_table,
                            const float* __restrict__ sv,
                            const float* __restrict__ rv,
                            const float* __restrict__ scorer_W,
                            const float* __restrict__ reuse_W,
                            const float* __restrict__ scorer_b,
                            const float* __restrict__ reuse_b,
                            float* __restrict__ logits,
                            float* __restrict__ out_reuse) {
    int b  = blockIdx.x >> 3;
    int l0 = (blockIdx.x & 7) * 128;
    int tid = threadIdx.x;
    __shared__ unsigned short hpS[16384];  // [k][tt][lane][8]
    __shared__ float s127[2];

    int w = tid >> 6;
    int lane = tid & 63;
    int ln = lane & 31, half = lane >> 5;

    // ---- 1. Q gather -> registers (issued first)
    int cl = cache_lines[b * LL + l0 + w * 32 + ln];
    const unsigned short* qrow = qT + (size_t)cl * D_ID + half * 8;
    s16x8 qf[8];
#pragma unroll
    for (int ks = 0; ks < 8; ++ks)
        qf[ks] = *(const s16x8*)(qrow + ks * 16);

    // ---- 2. hp projection: wave w owns d-rows [32w, 32w+32) x all 128 t
    {
        const float* arow = attn_W + (size_t)(32 * w + ln) * HH;
        const float* brow[4];
#pragma unroll
        for (int tt = 0; tt < 4; ++tt) {
            int t = tt * 32 + ln;
            brow[tt] = (t < TT - 1) ? history + ((size_t)b * (TT - 1) + t) * HH
                                    : h_new + (size_t)b * HH;
        }
        f32x16 pacc[4];
#pragma unroll
        for (int tt = 0; tt < 4; ++tt)
#pragma unroll
            for (int rr = 0; rr < 16; ++rr) pacc[tt][rr] = 0.f;

#pragma unroll 4
        for (int ks = 0; ks < 16; ++ks) {
            int off = ks * 16 + half * 8;
            float4 a0 = *(const float4*)(arow + off);
            float4 a1 = *(const float4*)(arow + off + 4);
            s16x8 af = pack8(a0, a1);
#pragma unroll
            for (int tt = 0; tt < 4; ++tt) {
                float4 b0 = *(const float4*)(brow[tt] + off);
                float4 b1 = *(const float4*)(brow[tt] + off + 4);
                pacc[tt] = __builtin_amdgcn_mfma_f32_32x32x16_bf16(
                    af, pack8(b0, b1), pacc[tt], 0, 0, 0);
            }
        }
        // C layout: d = 32w + (r&3)+8*(r>>2)+4*half, t = 32*tt + ln.
        // Store quads at the score-MFMA's B-fragment address.
#pragma unroll
        for (int tt = 0; tt < 4; ++tt)
#pragma unroll
            for (int qd = 0; qd < 4; ++qd) {
                u16x4 v;
                v[0] = f2bf(pacc[tt][4 * qd + 0]);
                v[1] = f2bf(pacc[tt][4 * qd + 1]);
                v[2] = f2bf(pacc[tt][4 * qd + 2]);
                v[3] = f2bf(pacc[tt][4 * qd + 3]);
                int sa = ((2 * w + (qd >> 1)) * 4 + tt) * 512 +
                         (qd & 1) * 256 + ln * 8 + 4 * half;
                *(u16x4*)(hpS + sa) = v;
            }
    }

    // ---- 3. sv/rv at t=127 (needs h_new)
    if (w < 2) {
        const float* wv = w ? reuse_W : scorer_W;
        float a = 0.f;
#pragma unroll
        for (int i = 0; i < 6; ++i) {
            int idx = lane + 64 * i;
            float x = (idx < HH)
                ? h_new[(size_t)b * HH + idx]
                : pos_table[(size_t)(TT - 1) * D_POS + (idx - HH)];
            a += wv[idx] * x;
        }
#pragma unroll
        for (int off = 1; off < 64; off <<= 1) a += __shfl_xor(a, off);
        if (lane == 0) s127[w] = a;
    }
    __syncthreads();

    // ---- 4. scores = Q @ hp^T, softmax over t, heads
    f32x16 acc[4];
#pragma unroll
    for (int tt = 0; tt < 4; ++tt)
#pragma unroll
        for (int rr = 0; rr < 16; ++rr) acc[tt][rr] = 0.f;

#pragma unroll
    for (int k = 0; k < 8; ++k) {
#pragma unroll
        for (int tt = 0; tt < 4; ++tt) {
            s16x8 bf = *(const s16x8*)(hpS + (k * 4 + tt) * 512 + lane * 8);
            acc[tt] = __builtin_amdgcn_mfma_f32_32x32x16_bf16(qf[k], bf, acc[tt], 0, 0, 0);
        }
    }

    float sv_r[4], rv_r[4];
#pragma unroll
    for (int tt = 0; tt < 4; ++tt) {
        sv_r[tt] = sv[b * TT + tt * 32 + ln];
        rv_r[tt] = rv[b * TT + tt * 32 + ln];
    }
    if (ln == 31) { sv_r[3] = s127[0]; rv_r[3] = s127[1]; }  // t=127 patch
    float sb = scorer_b[0], rb = reuse_b[0];

#pragma unroll
    for (int r = 0; r < 16; ++r) {
        float v0 = acc[0][r], v1 = acc[1][r], v2 = acc[2][r], v3 = acc[3][r];
        float m = fmaxf(fmaxf(v0, v1), fmaxf(v2, v3));
#pragma unroll
        for (int off = 1; off < 32; off <<= 1) m = fmaxf(m, __shfl_xor(m, off));
        float e0 = __expf(v0 - m), e1 = __expf(v1 - m),
              e2 = __expf(v2 - m), e3 = __expf(v3 - m);
        float s  = e0 + e1 + e2 + e3;
        float lg = e0 * sv_r[0] + e1 * sv_r[1] + e2 * sv_r[2] + e3 * sv_r[3];
        float rg = e0 * rv_r[0] + e1 * rv_r[1] + e2 * rv_r[2] + e3 * rv_r[3];
#pragma unroll
        for (int off = 1; off < 32; off <<= 1) {
            s  += __shfl_xor(s, off);
            lg += __shfl_xor(lg, off);
            rg += __shfl_xor(rg, off);
        }
        if (ln == 0) {
            int row = (r & 3) + 8 * (r >> 2) + 4 * half;
            int l = l0 + w * 32 + row;
            logits[b * LL + l] = lg / s + sb;
            out_reuse[b * LL + l] = rg / s + rb;
        }
    }
}

// -------------------------------------- masked softmax over L per batch
__global__ void finalsm_kernel(const float* __restrict__ logits,
                               const int* __restrict__ lengths,
                               float* __restrict__ out_probs) {
    int b = blockIdx.x;
    int tid = threadIdx.x;
    int valid = max(lengths[b], 1);
    float v[4];
    float m = -1e30f;
#pragma unroll
    for (int i = 0; i < 4; ++i) {
        int l = tid + 256 * i;
        v[i] = (l < valid) ? logits[b * LL + l] : -1e30f;
        m = fmaxf(m, v[i]);
    }
#pragma unroll
    for (int off = 1; off < 64; off <<= 1) m = fmaxf(m, __shfl_xor(m, off));
    __shared__ float redm[4];
    __shared__ float reds[4];
    int wave = tid >> 6;
    if ((tid & 63) == 0) redm[wave] = m;
    __syncthreads();
    m = fmaxf(fmaxf(redm[0], redm[1]), fmaxf(redm[2], redm[3]));
    float e[4];
    float s = 0.f;
#pragma unroll
    for (int i = 0; i < 4; ++i) {
        int l = tid + 256 * i;
        e[i] = (l < valid) ? expf(v[i] - m) : 0.f;
        s += e[i];
    }
#pragma unroll
    for (int off = 1; off < 64; off <<= 1) s += __shfl_xor(s, off);
    if ((tid & 63) == 0) reds[wave] = s;
    __syncthreads();
    s = reds[0] + reds[1] + reds[2] + reds[3];
    float inv = 1.f / s;
#pragma unroll
    for (int i = 0; i < 4; ++i)
        out_probs[b * LL + tid + 256 * i] = e[i] * inv;
}

extern "C" void kernel_launch(void* const* d_in, const int* in_sizes, int n_in,
                              void* d_out, int out_size, void* d_ws, size_t ws_size,
                              hipStream_t stream) {
    const int*   obj_id         = (const int*)d_in[0];
    const int*   obj_size       = (const int*)d_in[1];
    const int*   cache_lines    = (const int*)d_in[2];
    const int*   lengths        = (const int*)d_in[3];
    const float* c0             = (const float*)d_in[4];
    const float* h0             = (const float*)d_in[5];
    const float* history        = (const float*)d_in[6];
    const float* obj_id_table   = (const float*)d_in[7];
    const float* obj_size_table = (const float*)d_in[8];
    const float* pos_table      = (const float*)d_in[9];
    const float* W_ih           = (const float*)d_in[10];
    const float* W_hh           = (const float*)d_in[11];
    const float* b_ih           = (const float*)d_in[12];
    const float* b_hh           = (const float*)d_in[13];
    const float* attn_W         = (const float*)d_in[14];
    const float* scorer_W       = (const float*)d_in[15];
    const float* scorer_b       = (const float*)d_in[16];
    const float* reuse_W        = (const float*)d_in[17];
    const float* reuse_b        = (const float*)d_in[18];

    float* out = (float*)d_out;
    float* out_probs = out;                 // (B, L)
    float* out_reuse = out + BB * LL;       // (B, L)

    char* ws = (char*)d_ws;
    float*          h_new  = (float*)(ws);             // 64 KB
    float*          sv     = (float*)(ws + 65536);     // 32 KB
    float*          rv     = (float*)(ws + 98304);     // 32 KB
    float*          logits = (float*)(ws + 131072);    // 256 KB
    float*          xh_t   = (float*)(ws + 393216);    // 112 KB
    unsigned short* qT     = (unsigned short*)(ws + 1048576);  // 16 MB bf16

    // D1: embed + svrv(t<127) + table->bf16 convert (all independent)
    hipLaunchKernelGGL(prep_kernel, dim3(112 + 64 + 1024), dim3(256), 0, stream,
                       obj_id, obj_size, h0, obj_id_table, obj_size_table,
                       history, pos_table, scorer_W, reuse_W,
                       xh_t, sv, rv, qT);
    // D2: gates (round-0 form)
    hipLaunchKernelGGL(gates_kernel, dim3(HH), dim3(256), 0, stream,
                       xh_t, W_ih, W_hh, b_ih, b_hh, c0, h_new);
    // D3: attn (register-Q gather from qT + in-block hp projection)
    hipLaunchKernelGGL(attn_kernel, dim3(BB * 8), dim3(256), 0, stream,
                       cache_lines, qT, history, h_new, attn_W,
                       pos_table, sv, rv, scorer_W, reuse_W,
                       scorer_b, reuse_b, logits, out_reuse);
    // D4: masked softmax
    hipLaunchKernelGGL(finalsm_kernel, dim3(BB), dim3(256), 0, stream,
                       logits, lengths, out_probs);
}

// Round 3
// 165.319 us; speedup vs baseline: 1.2596x; 1.2596x over previous
//
#include <hip/hip_runtime.h>
#include <math.h>

#define BB 64
#define LL 1024
#define HH 256
#define TT 128
#define D_ID 128
#define D_SZ 64
#define D_POS 128
#define DX 192   // D_ID + D_SZ

typedef short s16x8 __attribute__((ext_vector_type(8)));
typedef float f32x16 __attribute__((ext_vector_type(16)));
typedef unsigned short u16x8 __attribute__((ext_vector_type(8)));

__device__ __forceinline__ unsigned short f2bf(float f) {
    unsigned u = __float_as_uint(f);
    unsigned r = u + 0x7fffu + ((u >> 16) & 1u);   // RNE
    return (unsigned short)(r >> 16);
}

__device__ __forceinline__ s16x8 pack8(float4 a, float4 b) {
    u16x8 p;
    p[0] = f2bf(a.x); p[1] = f2bf(a.y); p[2] = f2bf(a.z); p[3] = f2bf(a.w);
    p[4] = f2bf(b.x); p[5] = f2bf(b.y); p[6] = f2bf(b.z); p[7] = f2bf(b.w);
    return (s16x8)p;
}

// ------------------------------------------- xh_t[448][64] = concat(x, h0)^T
__global__ void embed_kernel(const int* __restrict__ obj_id,
                             const int* __restrict__ obj_size,
                             const float* __restrict__ h0,
                             const float* __restrict__ obj_id_table,
                             const float* __restrict__ obj_size_table,
                             float* __restrict__ xh_t) {
    int tid = threadIdx.x;
    int b = tid & 63;
    int k = blockIdx.x * 4 + (tid >> 6);
    float v;
    if (k < D_ID)      v = obj_id_table[(size_t)obj_id[b] * D_ID + k];
    else if (k < DX)   v = obj_size_table[(size_t)obj_size[b] * D_SZ + (k - D_ID)];
    else               v = h0[b * HH + (k - DX)];
    xh_t[k * 64 + b] = v;
}

// --------------- gates + fused LSTM activation (round-0 form)
__global__ void gates_kernel(const float* __restrict__ xh_t,
                             const float* __restrict__ W_ih,
                             const float* __restrict__ W_hh,
                             const float* __restrict__ b_ih,
                             const float* __restrict__ b_hh,
                             const float* __restrict__ c0,
                             float* __restrict__ h_new) {
    int j = blockIdx.x;
    int tid = threadIdx.x;
    int b = tid & 63;
    int q = __builtin_amdgcn_readfirstlane(tid >> 6);
    int r = q * HH + j;
    __shared__ float gS[256];

    float acc = b_ih[r] + b_hh[r];
    const float* wi = W_ih + (size_t)r * DX;
    const float* wh = W_hh + (size_t)r * HH;
#pragma unroll 16
    for (int k = 0; k < DX; ++k)
        acc += wi[k] * xh_t[k * 64 + b];
#pragma unroll 16
    for (int k = 0; k < HH; ++k)
        acc += wh[k] * xh_t[(DX + k) * 64 + b];
    gS[q * 64 + b] = acc;
    __syncthreads();

    if (tid < 64) {
        float ig = 1.f / (1.f + expf(-gS[tid]));
        float fg = 1.f / (1.f + expf(-gS[64 + tid]));
        float gg = tanhf(gS[128 + tid]);
        float og = 1.f / (1.f + expf(-gS[192 + tid]));
        float c = fg * c0[tid * HH + j] + ig * gg;
        h_new[tid * HH + j] = og * tanhf(c);
    }
}

// ------------- fused: HP(bf16) = hist @ attn_W^T (MFMA)  +  sv/rv dots
// (round-0 form; svrv covers ALL t incl. 127 since h_new is ready)
__global__ void proj_kernel(const float* __restrict__ history,
                            const float* __restrict__ h_new,
                            const float* __restrict__ attn_W,
                            const float* __restrict__ pos_table,
                            const float* __restrict__ scorer_W,
                            const float* __restrict__ reuse_W,
                            unsigned short* __restrict__ hp,
                            float* __restrict__ sv,
                            float* __restrict__ rv) {
    int blk = blockIdx.x;
    int tid = threadIdx.x;

    if (blk >= BB * 16) {
        // ---- svrv part: idx = b*4 + which*2 + thalf
        int idx = blk - BB * 16;
        int b = idx >> 2;
        int which = (idx >> 1) & 1;
        int t = (idx & 1) * 64 + tid;
        const float* w = which ? reuse_W : scorer_W;
        const float* hrow = (t < TT - 1)
            ? history + ((size_t)b * (TT - 1) + t) * HH
            : h_new + (size_t)b * HH;
        float acc = 0.f;
#pragma unroll 8
        for (int k = 0; k < HH / 4; ++k) {
            float4 hv = *(const float4*)(hrow + 4 * k);
            float4 wv = *(const float4*)(w + 4 * k);
            acc += hv.x * wv.x + hv.y * wv.y + hv.z * wv.z + hv.w * wv.w;
        }
        const float* prow = pos_table + (size_t)t * D_POS;
#pragma unroll 8
        for (int k = 0; k < D_POS / 4; ++k) {
            float4 pv = *(const float4*)(prow + 4 * k);
            float4 wv = *(const float4*)(w + HH + 4 * k);
            acc += pv.x * wv.x + pv.y * wv.y + pv.z * wv.z + pv.w * wv.w;
        }
        (which ? rv : sv)[b * TT + t] = acc;
        return;
    }

    // ---- proj part: one wave, direct-from-global MFMA fragments
    int b  = blk >> 4;
    int t0 = ((blk >> 2) & 3) * 32;
    int d0 = (blk & 3) * 32;
    int lane = tid;
    int ln = lane & 31, half = lane >> 5;

    int t = t0 + ln;
    const float* arow = (t < TT - 1)
        ? history + ((size_t)b * (TT - 1) + t) * HH
        : h_new + (size_t)b * HH;
    const float* brow = attn_W + (size_t)(d0 + ln) * HH;

    f32x16 acc;
#pragma unroll
    for (int r = 0; r < 16; ++r) acc[r] = 0.f;

#pragma unroll
    for (int ks = 0; ks < 16; ++ks) {
        int off = ks * 16 + half * 8;
        float4 a0 = *(const float4*)(arow + off);
        float4 a1 = *(const float4*)(arow + off + 4);
        float4 b0 = *(const float4*)(brow + off);
        float4 b1 = *(const float4*)(brow + off + 4);
        acc = __builtin_amdgcn_mfma_f32_32x32x16_bf16(
            pack8(a0, a1), pack8(b0, b1), acc, 0, 0, 0);
    }

#pragma unroll
    for (int r = 0; r < 16; ++r) {
        int tt = t0 + (r & 3) + 8 * (r >> 2) + 4 * half;
        hp[((size_t)b * TT + tt) * D_ID + d0 + ln] = f2bf(acc[r]);
    }
}

// ---- scores = Q@HP^T via mfma_32x32x16_bf16, softmax over t, heads.
// REWRITE (R3): zero LDS, zero barriers, single-wave 64-thread blocks,
// grid = B*32 (one wave per 32 l-rows). Q A-fragments gathered straight
// into registers (same pack8 bytes as the old qS path); B-fragments read
// DIRECTLY from global hp -- the fragment a lane needs is 16 contiguous
// bytes hp[t=32*tt+ln][k*16+half*8 ...], L2/L3-resident (2 MB).
// All ~50 loads per lane are independent -> max MLP for a latency-bound,
// grid-capped (8 waves/CU) kernel.
__global__ void __launch_bounds__(64, 2)
attn_kernel(const int* __restrict__ cache_lines,
            const float* __restrict__ obj_id_table,
            const unsigned short* __restrict__ hp,
            const float* __restrict__ sv,
            const float* __restrict__ rv,
            const float* __restrict__ scorer_b,
            const float* __restrict__ reuse_b,
            float* __restrict__ logits,
            float* __restrict__ out_reuse) {
    int b  = blockIdx.x >> 5;
    int l0 = (blockIdx.x & 31) * 32;
    int lane = threadIdx.x;
    int ln = lane & 31, half = lane >> 5;

    // ---- Q gather -> registers (issued first; bitwise same as old qS path)
    int cl = cache_lines[b * LL + l0 + ln];
    const float* qrow = obj_id_table + (size_t)cl * D_ID + half * 8;
    float4 qa[8], qb[8];
#pragma unroll
    for (int ks = 0; ks < 8; ++ks) {
        qa[ks] = *(const float4*)(qrow + ks * 16);
        qb[ks] = *(const float4*)(qrow + ks * 16 + 4);
    }

    // ---- sv/rv (independent loads, overlap the gather)
    float sv_r[4], rv_r[4];
#pragma unroll
    for (int tt = 0; tt < 4; ++tt) {
        sv_r[tt] = sv[b * TT + tt * 32 + ln];
        rv_r[tt] = rv[b * TT + tt * 32 + ln];
    }
    float sb = scorer_b[0], rb = reuse_b[0];

    s16x8 qf[8];
#pragma unroll
    for (int ks = 0; ks < 8; ++ks) qf[ks] = pack8(qa[ks], qb[ks]);

    // ---- scores = Q @ hp^T; B-fragments direct from global hp
    const unsigned short* hpb = hp + (size_t)b * TT * D_ID + half * 8;
    f32x16 acc[4];
#pragma unroll
    for (int tt = 0; tt < 4; ++tt)
#pragma unroll
        for (int r = 0; r < 16; ++r) acc[tt][r] = 0.f;

#pragma unroll
    for (int k = 0; k < 8; ++k) {
#pragma unroll
        for (int tt = 0; tt < 4; ++tt) {
            s16x8 bf = *(const s16x8*)(hpb + (size_t)(tt * 32 + ln) * D_ID + k * 16);
            acc[tt] = __builtin_amdgcn_mfma_f32_32x32x16_bf16(qf[k], bf, acc[tt], 0, 0, 0);
        }
    }

    // ---- softmax over t (per output row) + heads
#pragma unroll
    for (int r = 0; r < 16; ++r) {
        float v0 = acc[0][r], v1 = acc[1][r], v2 = acc[2][r], v3 = acc[3][r];
        float m = fmaxf(fmaxf(v0, v1), fmaxf(v2, v3));
#pragma unroll
        for (int off = 1; off < 32; off <<= 1) m = fmaxf(m, __shfl_xor(m, off));
        float e0 = __expf(v0 - m), e1 = __expf(v1 - m),
              e2 = __expf(v2 - m), e3 = __expf(v3 - m);
        float s  = e0 + e1 + e2 + e3;
        float lg = e0 * sv_r[0] + e1 * sv_r[1] + e2 * sv_r[2] + e3 * sv_r[3];
        float rg = e0 * rv_r[0] + e1 * rv_r[1] + e2 * rv_r[2] + e3 * rv_r[3];
#pragma unroll
        for (int off = 1; off < 32; off <<= 1) {
            s  += __shfl_xor(s, off);
            lg += __shfl_xor(lg, off);
            rg += __shfl_xor(rg, off);
        }
        if (ln == 0) {
            int row = (r & 3) + 8 * (r >> 2) + 4 * half;
            int l = l0 + row;
            logits[b * LL + l] = lg / s + sb;
            out_reuse[b * LL + l] = rg / s + rb;
        }
    }
}

// -------------------------------------- masked softmax over L per batch
__global__ void finalsm_kernel(const float* __restrict__ logits,
                               const int* __restrict__ lengths,
                               float* __restrict__ out_probs) {
    int b = blockIdx.x;
    int tid = threadIdx.x;
    int valid = max(lengths[b], 1);
    float v[4];
    float m = -1e30f;
#pragma unroll
    for (int i = 0; i < 4; ++i) {
        int l = tid + 256 * i;
        v[i] = (l < valid) ? logits[b * LL + l] : -1e30f;
        m = fmaxf(m, v[i]);
    }
#pragma unroll
    for (int off = 1; off < 64; off <<= 1) m = fmaxf(m, __shfl_xor(m, off));
    __shared__ float redm[4];
    __shared__ float reds[4];
    int wave = tid >> 6;
    if ((tid & 63) == 0) redm[wave] = m;
    __syncthreads();
    m = fmaxf(fmaxf(redm[0], redm[1]), fmaxf(redm[2], redm[3]));
    float e[4];
    float s = 0.f;
#pragma unroll
    for (int i = 0; i < 4; ++i) {
        int l = tid + 256 * i;
        e[i] = (l < valid) ? expf(v[i] - m) : 0.f;
        s += e[i];
    }
#pragma unroll
    for (int off = 1; off < 64; off <<= 1) s += __shfl_xor(s, off);
    if ((tid & 63) == 0) reds[wave] = s;
    __syncthreads();
    s = reds[0] + reds[1] + reds[2] + reds[3];
    float inv = 1.f / s;
#pragma unroll
    for (int i = 0; i < 4; ++i)
        out_probs[b * LL + tid + 256 * i] = e[i] * inv;
}

extern "C" void kernel_launch(void* const* d_in, const int* in_sizes, int n_in,
                              void* d_out, int out_size, void* d_ws, size_t ws_size,
                              hipStream_t stream) {
    const int*   obj_id         = (const int*)d_in[0];
    const int*   obj_size       = (const int*)d_in[1];
    const int*   cache_lines    = (const int*)d_in[2];
    const int*   lengths        = (const int*)d_in[3];
    const float* c0             = (const float*)d_in[4];
    const float* h0             = (const float*)d_in[5];
    const float* history        = (const float*)d_in[6];
    const float* obj_id_table   = (const float*)d_in[7];
    const float* obj_size_table = (const float*)d_in[8];
    const float* pos_table      = (const float*)d_in[9];
    const float* W_ih           = (const float*)d_in[10];
    const float* W_hh           = (const float*)d_in[11];
    const float* b_ih           = (const float*)d_in[12];
    const float* b_hh           = (const float*)d_in[13];
    const float* attn_W         = (const float*)d_in[14];
    const float* scorer_W       = (const float*)d_in[15];
    const float* scorer_b       = (const float*)d_in[16];
    const float* reuse_W        = (const float*)d_in[17];
    const float* reuse_b        = (const float*)d_in[18];

    float* out = (float*)d_out;
    float* out_probs = out;                 // (B, L)
    float* out_reuse = out + BB * LL;       // (B, L)

    char* ws = (char*)d_ws;
    float*          h_new  = (float*)(ws);                    // 64 KB
    unsigned short* hp     = (unsigned short*)(ws + 65536);   // 2 MB bf16
    float*          sv     = (float*)(ws + 65536 + 2097152);
    float*          rv     = (float*)(ws + 65536 + 2097152 + 32768);
    float*          xh_t   = (float*)(ws + 65536 + 2097152 + 65536);  // 112 KB
    float*          logits = (float*)(ws + 65536 + 2097152 + 65536);  // shares (disjoint lifetime)

    hipLaunchKernelGGL(embed_kernel, dim3(112), dim3(256), 0, stream,
                       obj_id, obj_size, h0, obj_id_table, obj_size_table, xh_t);
    hipLaunchKernelGGL(gates_kernel, dim3(HH), dim3(256), 0, stream,
                       xh_t, W_ih, W_hh, b_ih, b_hh, c0, h_new);
    hipLaunchKernelGGL(proj_kernel, dim3(BB * 16 + BB * 4), dim3(64), 0, stream,
                       history, h_new, attn_W, pos_table, scorer_W, reuse_W,
                       hp, sv, rv);
    hipLaunchKernelGGL(attn_kernel, dim3(BB * 32), dim3(64), 0, stream,
                       cache_lines, obj_id_table, hp, sv, rv,
                       scorer_b, reuse_b, logits, out_reuse);
    hipLaunchKernelGGL(finalsm_kernel, dim3(BB), dim3(256), 0, stream,
                       logits, lengths, out_probs);
}

// Round 4
// 164.256 us; speedup vs baseline: 1.2677x; 1.0065x over previous
//
#include <hip/hip_runtime.h>
#include <math.h>

#define BB 64
#define LL 1024
#define HH 256
#define TT 128
#define D_ID 128
#define D_SZ 64
#define D_POS 128
#define DX 192   // D_ID + D_SZ

typedef short s16x8 __attribute__((ext_vector_type(8)));
typedef float f32x16 __attribute__((ext_vector_type(16)));
typedef unsigned short u16x8 __attribute__((ext_vector_type(8)));

__device__ __forceinline__ unsigned short f2bf(float f) {
    unsigned u = __float_as_uint(f);
    unsigned r = u + 0x7fffu + ((u >> 16) & 1u);   // RNE
    return (unsigned short)(r >> 16);
}

__device__ __forceinline__ s16x8 pack8(float4 a, float4 b) {
    u16x8 p;
    p[0] = f2bf(a.x); p[1] = f2bf(a.y); p[2] = f2bf(a.z); p[3] = f2bf(a.w);
    p[4] = f2bf(b.x); p[5] = f2bf(b.y); p[6] = f2bf(b.z); p[7] = f2bf(b.w);
    return (s16x8)p;
}

// ------------------------------------------- xh_t[448][64] = concat(x, h0)^T
__global__ void embed_kernel(const int* __restrict__ obj_id,
                             const int* __restrict__ obj_size,
                             const float* __restrict__ h0,
                             const float* __restrict__ obj_id_table,
                             const float* __restrict__ obj_size_table,
                             float* __restrict__ xh_t) {
    int tid = threadIdx.x;
    int b = tid & 63;
    int k = blockIdx.x * 4 + (tid >> 6);
    float v;
    if (k < D_ID)      v = obj_id_table[(size_t)obj_id[b] * D_ID + k];
    else if (k < DX)   v = obj_size_table[(size_t)obj_size[b] * D_SZ + (k - D_ID)];
    else               v = h0[b * HH + (k - DX)];
    xh_t[k * 64 + b] = v;
}

// --------------- gates + fused LSTM activation (round-0 form)
__global__ void gates_kernel(const float* __restrict__ xh_t,
                             const float* __restrict__ W_ih,
                             const float* __restrict__ W_hh,
                             const float* __restrict__ b_ih,
                             const float* __restrict__ b_hh,
                             const float* __restrict__ c0,
                             float* __restrict__ h_new) {
    int j = blockIdx.x;
    int tid = threadIdx.x;
    int b = tid & 63;
    int q = __builtin_amdgcn_readfirstlane(tid >> 6);
    int r = q * HH + j;
    __shared__ float gS[256];

    float acc = b_ih[r] + b_hh[r];
    const float* wi = W_ih + (size_t)r * DX;
    const float* wh = W_hh + (size_t)r * HH;
#pragma unroll 16
    for (int k = 0; k < DX; ++k)
        acc += wi[k] * xh_t[k * 64 + b];
#pragma unroll 16
    for (int k = 0; k < HH; ++k)
        acc += wh[k] * xh_t[(DX + k) * 64 + b];
    gS[q * 64 + b] = acc;
    __syncthreads();

    if (tid < 64) {
        float ig = 1.f / (1.f + expf(-gS[tid]));
        float fg = 1.f / (1.f + expf(-gS[64 + tid]));
        float gg = tanhf(gS[128 + tid]);
        float og = 1.f / (1.f + expf(-gS[192 + tid]));
        float c = fg * c0[tid * HH + j] + ig * gg;
        h_new[tid * HH + j] = og * tanhf(c);
    }
}

// ------------- fused: HP(bf16) = hist @ attn_W^T (MFMA)  +  sv/rv dots
// XCD swizzle (R4): all blocks sharing a batch b get the same
// (blockIdx mod 8) -> same XCD L2 (round-robin dispatch) -> history[b]
// (127 KB) and attn_W are fetched ONCE per XCD instead of up to 8x.
// Decode is bijective; grid = 1280 = 8*160. Pure remap, no numeric change.
__global__ void proj_kernel(const float* __restrict__ history,
                            const float* __restrict__ h_new,
                            const float* __restrict__ attn_W,
                            const float* __restrict__ pos_table,
                            const float* __restrict__ scorer_W,
                            const float* __restrict__ reuse_W,
                            unsigned short* __restrict__ hp,
                            float* __restrict__ sv,
                            float* __restrict__ rv) {
    int blk = blockIdx.x;
    int tid = threadIdx.x;

    if (blk >= BB * 16) {
        // ---- svrv part: idx in [0,256) -> b on XCD (idx&7)
        int idx = blk - BB * 16;
        int b = (idx & 7) + 8 * ((idx >> 3) & 7);
        int rest = idx >> 6;              // [0,4)
        int which = rest >> 1;
        int t = (rest & 1) * 64 + tid;
        const float* w = which ? reuse_W : scorer_W;
        const float* hrow = (t < TT - 1)
            ? history + ((size_t)b * (TT - 1) + t) * HH
            : h_new + (size_t)b * HH;
        float acc = 0.f;
#pragma unroll 8
        for (int k = 0; k < HH / 4; ++k) {
            float4 hv = *(const float4*)(hrow + 4 * k);
            float4 wv = *(const float4*)(w + 4 * k);
            acc += hv.x * wv.x + hv.y * wv.y + hv.z * wv.z + hv.w * wv.w;
        }
        const float* prow = pos_table + (size_t)t * D_POS;
#pragma unroll 8
        for (int k = 0; k < D_POS / 4; ++k) {
            float4 pv = *(const float4*)(prow + 4 * k);
            float4 wv = *(const float4*)(w + HH + 4 * k);
            acc += pv.x * wv.x + pv.y * wv.y + pv.z * wv.z + pv.w * wv.w;
        }
        (which ? rv : sv)[b * TT + t] = acc;
        return;
    }

    // ---- proj part: i in [0,1024): b = (i&7)+8*((i>>3)&7), inner = i>>6
    int b = (blk & 7) + 8 * ((blk >> 3) & 7);
    int inner = blk >> 6;                 // [0,16)
    int t0 = ((inner >> 2) & 3) * 32;
    int d0 = (inner & 3) * 32;
    int lane = tid;
    int ln = lane & 31, half = lane >> 5;

    int t = t0 + ln;
    const float* arow = (t < TT - 1)
        ? history + ((size_t)b * (TT - 1) + t) * HH
        : h_new + (size_t)b * HH;
    const float* brow = attn_W + (size_t)(d0 + ln) * HH;

    f32x16 acc;
#pragma unroll
    for (int r = 0; r < 16; ++r) acc[r] = 0.f;

#pragma unroll
    for (int ks = 0; ks < 16; ++ks) {
        int off = ks * 16 + half * 8;
        float4 a0 = *(const float4*)(arow + off);
        float4 a1 = *(const float4*)(arow + off + 4);
        float4 b0 = *(const float4*)(brow + off);
        float4 b1 = *(const float4*)(brow + off + 4);
        acc = __builtin_amdgcn_mfma_f32_32x32x16_bf16(
            pack8(a0, a1), pack8(b0, b1), acc, 0, 0, 0);
    }

#pragma unroll
    for (int r = 0; r < 16; ++r) {
        int tt = t0 + (r & 3) + 8 * (r >> 2) + 4 * half;
        hp[((size_t)b * TT + tt) * D_ID + d0 + ln] = f2bf(acc[r]);
    }
}

// ---- scores = Q@HP^T via mfma_32x32x16_bf16, softmax over t, heads.
// R3 form (zero LDS / zero barriers / 64-thread single-wave blocks) +
// R4 XCD swizzle: the 32 waves sharing batch b land on one XCD ->
// hp[b] (32 KB) is L2-local after first touch (was fetched up to 8x
// across XCDs). Grid 2048 = 8*256, bijective remap only.
__global__ void __launch_bounds__(64, 2)
attn_kernel(const int* __restrict__ cache_lines,
            const float* __restrict__ obj_id_table,
            const unsigned short* __restrict__ hp,
            const float* __restrict__ sv,
            const float* __restrict__ rv,
            const float* __restrict__ scorer_b,
            const float* __restrict__ reuse_b,
            float* __restrict__ logits,
            float* __restrict__ out_reuse) {
    int i  = blockIdx.x;
    int b  = (i & 7) + 8 * ((i >> 3) & 7);
    int l0 = (i >> 6) * 32;
    int lane = threadIdx.x;
    int ln = lane & 31, half = lane >> 5;

    // ---- Q gather -> registers (issued first; bitwise same as qS path)
    int cl = cache_lines[b * LL + l0 + ln];
    const float* qrow = obj_id_table + (size_t)cl * D_ID + half * 8;
    float4 qa[8], qb[8];
#pragma unroll
    for (int ks = 0; ks < 8; ++ks) {
        qa[ks] = *(const float4*)(qrow + ks * 16);
        qb[ks] = *(const float4*)(qrow + ks * 16 + 4);
    }

    // ---- sv/rv (independent loads, overlap the gather)
    float sv_r[4], rv_r[4];
#pragma unroll
    for (int tt = 0; tt < 4; ++tt) {
        sv_r[tt] = sv[b * TT + tt * 32 + ln];
        rv_r[tt] = rv[b * TT + tt * 32 + ln];
    }
    float sb = scorer_b[0], rb = reuse_b[0];

    s16x8 qf[8];
#pragma unroll
    for (int ks = 0; ks < 8; ++ks) qf[ks] = pack8(qa[ks], qb[ks]);

    // ---- scores = Q @ hp^T; B-fragments direct from (XCD-local) hp
    const unsigned short* hpb = hp + (size_t)b * TT * D_ID + half * 8;
    f32x16 acc[4];
#pragma unroll
    for (int tt = 0; tt < 4; ++tt)
#pragma unroll
        for (int r = 0; r < 16; ++r) acc[tt][r] = 0.f;

#pragma unroll
    for (int k = 0; k < 8; ++k) {
#pragma unroll
        for (int tt = 0; tt < 4; ++tt) {
            s16x8 bf = *(const s16x8*)(hpb + (size_t)(tt * 32 + ln) * D_ID + k * 16);
            acc[tt] = __builtin_amdgcn_mfma_f32_32x32x16_bf16(qf[k], bf, acc[tt], 0, 0, 0);
        }
    }

    // ---- softmax over t (per output row) + heads
#pragma unroll
    for (int r = 0; r < 16; ++r) {
        float v0 = acc[0][r], v1 = acc[1][r], v2 = acc[2][r], v3 = acc[3][r];
        float m = fmaxf(fmaxf(v0, v1), fmaxf(v2, v3));
#pragma unroll
        for (int off = 1; off < 32; off <<= 1) m = fmaxf(m, __shfl_xor(m, off));
        float e0 = __expf(v0 - m), e1 = __expf(v1 - m),
              e2 = __expf(v2 - m), e3 = __expf(v3 - m);
        float s  = e0 + e1 + e2 + e3;
        float lg = e0 * sv_r[0] + e1 * sv_r[1] + e2 * sv_r[2] + e3 * sv_r[3];
        float rg = e0 * rv_r[0] + e1 * rv_r[1] + e2 * rv_r[2] + e3 * rv_r[3];
#pragma unroll
        for (int off = 1; off < 32; off <<= 1) {
            s  += __shfl_xor(s, off);
            lg += __shfl_xor(lg, off);
            rg += __shfl_xor(rg, off);
        }
        if (ln == 0) {
            int row = (r & 3) + 8 * (r >> 2) + 4 * half;
            int l = l0 + row;
            logits[b * LL + l] = lg / s + sb;
            out_reuse[b * LL + l] = rg / s + rb;
        }
    }
}

// -------------------------------------- masked softmax over L per batch
__global__ void finalsm_kernel(const float* __restrict__ logits,
                               const int* __restrict__ lengths,
                               float* __restrict__ out_probs) {
    int b = blockIdx.x;
    int tid = threadIdx.x;
    int valid = max(lengths[b], 1);
    float v[4];
    float m = -1e30f;
#pragma unroll
    for (int i = 0; i < 4; ++i) {
        int l = tid + 256 * i;
        v[i] = (l < valid) ? logits[b * LL + l] : -1e30f;
        m = fmaxf(m, v[i]);
    }
#pragma unroll
    for (int off = 1; off < 64; off <<= 1) m = fmaxf(m, __shfl_xor(m, off));
    __shared__ float redm[4];
    __shared__ float reds[4];
    int wave = tid >> 6;
    if ((tid & 63) == 0) redm[wave] = m;
    __syncthreads();
    m = fmaxf(fmaxf(redm[0], redm[1]), fmaxf(redm[2], redm[3]));
    float e[4];
    float s = 0.f;
#pragma unroll
    for (int i = 0; i < 4; ++i) {
        int l = tid + 256 * i;
        e[i] = (l < valid) ? expf(v[i] - m) : 0.f;
        s += e[i];
    }
#pragma unroll
    for (int off = 1; off < 64; off <<= 1) s += __shfl_xor(s, off);
    if ((tid & 63) == 0) reds[wave] = s;
    __syncthreads();
    s = reds[0] + reds[1] + reds[2] + reds[3];
    float inv = 1.f / s;
#pragma unroll
    for (int i = 0; i < 4; ++i)
        out_probs[b * LL + tid + 256 * i] = e[i] * inv;
}

extern "C" void kernel_launch(void* const* d_in, const int* in_sizes, int n_in,
                              void* d_out, int out_size, void* d_ws, size_t ws_size,
                              hipStream_t stream) {
    const int*   obj_id         = (const int*)d_in[0];
    const int*   obj_size       = (const int*)d_in[1];
    const int*   cache_lines    = (const int*)d_in[2];
    const int*   lengths        = (const int*)d_in[3];
    const float* c0             = (const float*)d_in[4];
    const float* h0             = (const float*)d_in[5];
    const float* history        = (const float*)d_in[6];
    const float* obj_id_table   = (const float*)d_in[7];
    const float* obj_size_table = (const float*)d_in[8];
    const float* pos_table      = (const float*)d_in[9];
    const float* W_ih           = (const float*)d_in[10];
    const float* W_hh           = (const float*)d_in[11];
    const float* b_ih           = (const float*)d_in[12];
    const float* b_hh           = (const float*)d_in[13];
    const float* attn_W         = (const float*)d_in[14];
    const float* scorer_W       = (const float*)d_in[15];
    const float* scorer_b       = (const float*)d_in[16];
    const float* reuse_W        = (const float*)d_in[17];
    const float* reuse_b        = (const float*)d_in[18];

    float* out = (float*)d_out;
    float* out_probs = out;                 // (B, L)
    float* out_reuse = out + BB * LL;       // (B, L)

    char* ws = (char*)d_ws;
    float*          h_new  = (float*)(ws);                    // 64 KB
    unsigned short* hp     = (unsigned short*)(ws + 65536);   // 2 MB bf16
    float*          sv     = (float*)(ws + 65536 + 2097152);
    float*          rv     = (float*)(ws + 65536 + 2097152 + 32768);
    float*          xh_t   = (float*)(ws + 65536 + 2097152 + 65536);  // 112 KB
    float*          logits = (float*)(ws + 65536 + 2097152 + 65536);  // shares (disjoint lifetime)

    hipLaunchKernelGGL(embed_kernel, dim3(112), dim3(256), 0, stream,
                       obj_id, obj_size, h0, obj_id_table, obj_size_table, xh_t);
    hipLaunchKernelGGL(gates_kernel, dim3(HH), dim3(256), 0, stream,
                       xh_t, W_ih, W_hh, b_ih, b_hh, c0, h_new);
    hipLaunchKernelGGL(proj_kernel, dim3(BB * 16 + BB * 4), dim3(64), 0, stream,
                       history, h_new, attn_W, pos_table, scorer_W, reuse_W,
                       hp, sv, rv);
    hipLaunchKernelGGL(attn_kernel, dim3(BB * 32), dim3(64), 0, stream,
                       cache_lines, obj_id_table, hp, sv, rv,
                       scorer_b, reuse_b, logits, out_reuse);
    hipLaunchKernelGGL(finalsm_kernel, dim3(BB), dim3(256), 0, stream,
                       logits, lengths, out_probs);
}